// Round 4
// baseline (193.098 us; speedup 1.0000x reference)
//
#include <hip/hip_runtime.h>

// NavierStokesLoss: fused jet-propagation (value + 4 first-order + 3 second-order
// tangents = 8 channels/point) through 4->256->256->5 tanh MLP, bf16 MFMA for the
// 256x256 layer, f32 everywhere else.
// R4: occupancy play. BP=8, M=64, 32 KiB LDS, acc[2][4] (32 AGPR),
//     launch_bounds(512,6) -> 3 blocks/CU. Row layout keeps channel halves
//     16 rows apart so recombine stays register-local at 32-row wave tiles.

#define NPTS 65536
#define BP   8
#define NBLK (NPTS / BP)      // 8192
#define KPAD 264              // padded k-stride of W2^T (bf16 elems); 528B = 33*16B
#define W3T_OFF 135168        // 256*264*2
#define PART_OFF 143360       // W3T_OFF + 16*256*2 ; parts = 8192*2 f32 = 64 KiB

typedef short s16x8 __attribute__((ext_vector_type(8)));
typedef float f32x4 __attribute__((ext_vector_type(4)));

static __device__ __forceinline__ unsigned short f2bf(float f){
  unsigned int u = __float_as_uint(f);
  u = (u + 0x7FFFu + ((u >> 16) & 1u)) >> 16;   // RNE
  return (unsigned short)u;
}
static __device__ __forceinline__ unsigned cvtpk_bf16(float lo, float hi){
  unsigned r;
  asm("v_cvt_pk_bf16_f32 %0, %1, %2" : "=v"(r) : "v"(lo), "v"(hi));
  return r;
}
static __device__ __forceinline__ float fast_tanh(float x){
  float e = exp2f(x * 2.8853900817779268f);     // exp(2x)
  return 1.f - 2.f * __builtin_amdgcn_rcpf(e + 1.f);
}

// W2 (256x256 f32, [k][j]) -> w2t bf16 [j][KPAD] (transposed, padded)
__global__ void prep_w2t(const float* __restrict__ W2, unsigned short* __restrict__ w2t){
  int k = blockIdx.x, j = threadIdx.x;
  w2t[j * KPAD + k] = f2bf(W2[k * 256 + j]);
}

// W3 (256x5 f32, [k][n]) -> w3t bf16 [16][256] (transposed, rows 5..15 zero)
__global__ void prep_w3t(const float* __restrict__ W3, unsigned short* __restrict__ w3t){
  int idx = blockIdx.x * 256 + threadIdx.x;
  int n = idx >> 8, k = idx & 255;
  w3t[n * 256 + k] = (n < 5) ? f2bf(W3[k * 5 + n]) : (unsigned short)0;
}

// Row layout of the 64x256 jet tile:
//   row(p,c) = (p&4)*8 + (c&4)*4 + (p&3)*4 + (c&3)
// points 0-3 -> rows 0-31 (wr=0), points 4-7 -> rows 32-63 (wr=1);
// within a 32-row half, channels 0-3 in rows 0-15, channels 4-7 in rows 16-31,
// so acc[0][nt] / acc[1][nt] of one lane hold channel c / c+4 of one point.
__launch_bounds__(512, 6)
__global__ void ns_main(const float* __restrict__ pts, const float* __restrict__ times,
                        const float* __restrict__ visc,
                        const float* __restrict__ W1, const float* __restrict__ b1,
                        const float* __restrict__ b2, const float* __restrict__ b3,
                        const unsigned short* __restrict__ w2t,
                        const unsigned short* __restrict__ w3t,
                        float* __restrict__ parts){
  __shared__ __align__(16) unsigned char sA[64 * 512];   // 32 KiB

  const int t   = threadIdx.x;
  const int blk = blockIdx.x;

  // ---------------- layer 1: seed the jet, write bf16 A-tile ----------------
  {
    int p  = t >> 6;            // 8 points, one wave each
    int jo = (t & 63) << 2;     // 4 consecutive j per thread
    int n  = blk * BP + p;
    float z0 = pts[n*3+0], z1 = pts[n*3+1], z2 = pts[n*3+2], z3 = times[n];
    float4 wa = *(const float4*)(W1 + jo);
    float4 wb = *(const float4*)(W1 + 256 + jo);
    float4 wc4 = *(const float4*)(W1 + 512 + jo);
    float4 wd = *(const float4*)(W1 + 768 + jo);
    float4 bb = *(const float4*)(b1 + jo);
    float th[4], sg[4], m2[4];
    #pragma unroll
    for (int jj = 0; jj < 4; ++jj){
      float a = (&bb.x)[jj] + z0*(&wa.x)[jj] + z1*(&wb.x)[jj]
                            + z2*(&wc4.x)[jj] + z3*(&wd.x)[jj];
      float h = fast_tanh(a);
      th[jj] = h;
      sg[jj] = 1.f - h*h;
      m2[jj] = -2.f * h * sg[jj];
    }
    #pragma unroll
    for (int c = 0; c < 8; ++c){
      float x[4];
      #pragma unroll
      for (int jj = 0; jj < 4; ++jj){
        float w0 = (&wa.x)[jj], w1 = (&wb.x)[jj], w2 = (&wc4.x)[jj];
        float v;
        if      (c == 0) v = th[jj];
        else if (c == 1) v = sg[jj]*w0;
        else if (c == 2) v = sg[jj]*w1;
        else if (c == 3) v = sg[jj]*w2;
        else if (c == 4) v = sg[jj]*(&wd.x)[jj];
        else if (c == 5) v = m2[jj]*w0*w0;
        else if (c == 6) v = m2[jj]*w1*w1;
        else             v = m2[jj]*w2*w2;
        x[jj] = v;
      }
      int row = ((p & 4) << 3) + ((c & 4) << 2) + ((p & 3) << 2) + (c & 3);
      int off = row*512 + ((jo << 1) ^ ((row & 7) << 4));
      uint2 v2;
      v2.x = cvtpk_bf16(x[0], x[1]);
      v2.y = cvtpk_bf16(x[2], x[3]);
      *(uint2*)(sA + off) = v2;
    }
  }
  __syncthreads();

  const int wid = t >> 6, lane = t & 63;
  const int g = lane >> 4, r16 = lane & 15;
  const int wr = wid >> 2, wc = wid & 3;       // 2x4 wave grid over 64x256 C
  const int xorv = (r16 & 7) << 4;

  // ---------------- GEMM2: A(64x256) @ W2(256x256), bf16 MFMA ----------------
  // wave tile 32x64: acc[mt][nt], rows wr*32+mt*16, cols wc*64+nt*16
  f32x4 acc[2][4];
  #pragma unroll
  for (int a = 0; a < 2; ++a)
    #pragma unroll
    for (int b = 0; b < 4; ++b)
      acc[a][b] = (f32x4){0.f, 0.f, 0.f, 0.f};

  {
    const unsigned char* w2tB = (const unsigned char*)w2t;
    int abase = (wr*32 + r16)*512;
    const unsigned char* bptr[4];
    #pragma unroll
    for (int nt = 0; nt < 4; ++nt)
      bptr[nt] = w2tB + (((wc*64 + nt*16 + r16)*KPAD + g*8) << 1);
    #pragma unroll
    for (int ks = 0; ks < 8; ++ks){
      int k0 = ks * 32;
      int X  = ((k0 << 1) + (g << 4)) ^ xorv;
      s16x8 af[2], bfr[4];
      af[0] = *(const s16x8*)(sA + abase + X);
      af[1] = *(const s16x8*)(sA + abase + 8192 + X);
      #pragma unroll
      for (int nt = 0; nt < 4; ++nt)
        bfr[nt] = *(const s16x8*)(bptr[nt] + (k0 << 1));
      #pragma unroll
      for (int mt = 0; mt < 2; ++mt)
        #pragma unroll
        for (int nt = 0; nt < 4; ++nt)
          acc[mt][nt] = __builtin_amdgcn_mfma_f32_16x16x32_bf16(af[mt], bfr[nt], acc[mt][nt], 0, 0, 0);
    }
  }
  __syncthreads();   // all A-tile reads complete before overwrite

  // ------- recombine (tanh jet through layer-2), register-local, imm-offset writes -------
  {
    float b2c[4];
    #pragma unroll
    for (int nt = 0; nt < 4; ++nt) b2c[nt] = b2[wc*64 + nt*16 + r16];
    // write row for channel c3 (<4): wr*32 + g*4 + c3 ; +16 rows (+8192 B) for c3+4
    // row&7 = (g&1)*4 + c3 for both halves
    int wadr[4][4];
    #pragma unroll
    for (int nt = 0; nt < 4; ++nt){
      int colb = (wc*64 + nt*16 + r16) << 1;
      #pragma unroll
      for (int c3 = 0; c3 < 4; ++c3)
        wadr[nt][c3] = (wr*32 + g*4 + c3)*512 + (colb ^ ((((g & 1) << 2) + c3) << 4));
    }
    #pragma unroll
    for (int nt = 0; nt < 4; ++nt){
      f32x4 v = acc[0][nt];       // channels 0..3: value, dx, dy, dz
      f32x4 w = acc[1][nt];       // channels 4..7: dt, dxx, dyy, dzz
      float gv = fast_tanh(v[0] + b2c[nt]);
      float s2 = 1.f - gv*gv;
      float t2 = -2.f * gv * s2;
      float r0 = gv,      r1 = s2*v[1], r2 = s2*v[2], r3 = s2*v[3];
      float r4 = s2*w[0];
      float r5 = fmaf(t2*v[1], v[1], s2*w[1]);
      float r6 = fmaf(t2*v[2], v[2], s2*w[2]);
      float r7 = fmaf(t2*v[3], v[3], s2*w[3]);
      unsigned u;
      u = cvtpk_bf16(r0, r4);
      *(unsigned short*)(sA + wadr[nt][0])        = (unsigned short)u;
      *(unsigned short*)(sA + wadr[nt][0] + 8192) = (unsigned short)(u >> 16);
      u = cvtpk_bf16(r1, r5);
      *(unsigned short*)(sA + wadr[nt][1])        = (unsigned short)u;
      *(unsigned short*)(sA + wadr[nt][1] + 8192) = (unsigned short)(u >> 16);
      u = cvtpk_bf16(r2, r6);
      *(unsigned short*)(sA + wadr[nt][2])        = (unsigned short)u;
      *(unsigned short*)(sA + wadr[nt][2] + 8192) = (unsigned short)(u >> 16);
      u = cvtpk_bf16(r3, r7);
      *(unsigned short*)(sA + wadr[nt][3])        = (unsigned short)u;
      *(unsigned short*)(sA + wadr[nt][3] + 8192) = (unsigned short)(u >> 16);
    }
  }
  __syncthreads();

  // ---------------- GEMM3: B(64x256) @ W3pad(256x16), waves 0-3 ----------------
  if (wid < 4){
    f32x4 acc3 = (f32x4){0.f, 0.f, 0.f, 0.f};
    int rbase = (wid*16 + r16)*512;
    const unsigned char* w3tB = (const unsigned char*)w3t + ((r16*256 + g*8) << 1);
    #pragma unroll
    for (int ks = 0; ks < 8; ++ks){
      int k0 = ks * 32;
      int X  = ((k0 << 1) + (g << 4)) ^ xorv;
      s16x8 a3  = *(const s16x8*)(sA + rbase + X);
      s16x8 b3f = *(const s16x8*)(w3tB + (k0 << 1));
      acc3 = __builtin_amdgcn_mfma_f32_16x16x32_bf16(a3, b3f, acc3, 0, 0, 0);
    }
    // write the 5 useful outputs into the first bytes of each row (bank-XOR'd)
    if (r16 < 5){
      #pragma unroll
      for (int q = 0; q < 4; ++q){
        int row = wid*16 + g*4 + q;
        *(float*)(sA + row*512 + ((r16 << 2) ^ ((row & 7) << 4))) = acc3[q];
      }
    }
  }
  __syncthreads();

  // ---------------- per-point residual assembly (wave 0) ----------------
  float m_part = 0.f, c_part = 0.f;
  if (t < 8){
    int p = t, n = blk*BP + p;
    float o[8][5];
    #pragma unroll
    for (int c = 0; c < 8; ++c){
      int row = ((p & 4) << 3) + ((c & 4) << 2) + ((p & 3) << 2) + (c & 3);
      int swz = (row & 7) << 4;
      f32x4 v4 = *(const f32x4*)(sA + row*512 + swz);
      o[c][0] = v4[0]; o[c][1] = v4[1]; o[c][2] = v4[2]; o[c][3] = v4[3];
      o[c][4] = *(const float*)(sA + row*512 + (16 ^ swz));
    }
    #pragma unroll
    for (int m = 0; m < 5; ++m) o[0][m] += b3[m];  // bias only on value channel

    float u0 = o[0][0], u1 = o[0][1], u2 = o[0][2];
    float rho = 1000.f * (1.f + 0.1f * fast_tanh(o[0][4]));
    float rr  = __builtin_amdgcn_rcpf(rho);
    float vis = visc[n];

    float conv0 = u0*o[1][0] + u1*o[2][0] + u2*o[3][0];
    float conv1 = u0*o[1][1] + u1*o[2][1] + u2*o[3][1];
    float conv2 = u0*o[1][2] + u1*o[2][2] + u2*o[3][2];
    float lap0 = o[5][0] + o[6][0] + o[7][0];
    float lap1 = o[5][1] + o[6][1] + o[7][1];
    float lap2 = o[5][2] + o[6][2] + o[7][2];
    float R0 = o[4][0] + conv0 + o[1][3]*rr - vis*lap0;
    float R1 = o[4][1] + conv1 + o[2][3]*rr - vis*lap1 + 9.81f;
    float R2 = o[4][2] + conv2 + o[3][3]*rr - vis*lap2;
    float Rc = o[1][0] + o[2][1] + o[3][2];

    m_part = R0*R0 + R1*R1 + R2*R2;
    c_part = Rc*Rc;
  }
  if (t < 64){
    #pragma unroll
    for (int off = 1; off < 8; off <<= 1){
      m_part += __shfl_xor(m_part, off, 64);
      c_part += __shfl_xor(c_part, off, 64);
    }
    if (t == 0){
      float2 pr; pr.x = m_part; pr.y = c_part;
      *(float2*)(parts + blk*2) = pr;
    }
  }
}

__global__ void ns_reduce(const float* __restrict__ parts, float* __restrict__ out){
  int t = threadIdx.x;
  float a = 0.f, b = 0.f;
  for (int i = t; i < NBLK; i += 256){ a += parts[2*i]; b += parts[2*i + 1]; }
  #pragma unroll
  for (int off = 32; off; off >>= 1){
    a += __shfl_down(a, off, 64);
    b += __shfl_down(b, off, 64);
  }
  __shared__ float sa[4], sb[4];
  int wid = t >> 6, lane = t & 63;
  if (lane == 0){ sa[wid] = a; sb[wid] = b; }
  __syncthreads();
  if (t == 0){
    float A = sa[0] + sa[1] + sa[2] + sa[3];
    float B = sb[0] + sb[1] + sb[2] + sb[3];
    float mom  = A / (float)NPTS;
    float cont = B / (float)NPTS;
    out[0] = mom + 10.f * cont;
    out[1] = mom;
    out[2] = cont;
  }
}

extern "C" void kernel_launch(void* const* d_in, const int* in_sizes, int n_in,
                              void* d_out, int out_size, void* d_ws, size_t ws_size,
                              hipStream_t stream) {
  const float* pts   = (const float*)d_in[0];
  const float* times = (const float*)d_in[1];
  const float* visc  = (const float*)d_in[2];
  const float* W1    = (const float*)d_in[3];
  const float* b1    = (const float*)d_in[4];
  const float* W2    = (const float*)d_in[5];
  const float* b2    = (const float*)d_in[6];
  const float* W3    = (const float*)d_in[7];
  const float* b3    = (const float*)d_in[8];
  float* out = (float*)d_out;

  unsigned short* w2t = (unsigned short*)d_ws;
  unsigned short* w3t = (unsigned short*)((char*)d_ws + W3T_OFF);
  float* parts        = (float*)((char*)d_ws + PART_OFF);

  prep_w2t<<<256, 256, 0, stream>>>(W2, w2t);
  prep_w3t<<<16, 256, 0, stream>>>(W3, w3t);
  ns_main<<<NBLK, 512, 0, stream>>>(pts, times, visc, W1, b1, b2, b3, w2t, w3t, parts);
  ns_reduce<<<1, 256, 0, stream>>>(parts, out);
}